// Round 1
// baseline (2625.224 us; speedup 1.0000x reference)
//
#include <hip/hip_runtime.h>

typedef unsigned int uint;
typedef _Float16 f16;
typedef _Float16 f16x2 __attribute__((ext_vector_type(2)));
typedef _Float16 f16x4 __attribute__((ext_vector_type(4)));
typedef _Float16 f16x8 __attribute__((ext_vector_type(8)));
typedef float f32x4 __attribute__((ext_vector_type(4)));

#define B_ 64
#define T_ 1024
#define I_ 128
#define H_ 256

// ---------------- prep: transpose x-part weights to [512 cols][K] fp16 ----------------
template<int KIN>
__global__ void prep_wxt(const float* __restrict__ Wf, const float* __restrict__ Wc,
                         f16* __restrict__ WxT) {
  int o = blockIdx.x * 256 + threadIdx.x;
  if (o >= 512 * KIN) return;
  int n = o / KIN, k = o % KIN;
  float v = (n < 256) ? Wf[k * H_ + n] : Wc[k * H_ + (n - 256)];
  WxT[o] = (f16)v;
}

// ---------------- prep: transpose recurrent weights to UT[512 n][256 k] fp16 ----------
// UT[n][k] = W[(DIN+k)*H + (n&255)], gate = n>>8 (0=f from Wf, 1=c from Wc)
__global__ void prep_ut(const float* __restrict__ Wf, const float* __restrict__ Wc,
                        f16* __restrict__ UT, int DIN) {
  int o = blockIdx.x * 256 + threadIdx.x;   // 512*256 = 131072
  int n = o >> 8, k = o & 255;
  const float* W = (n < 256) ? Wf : Wc;
  UT[o] = (f16)W[(DIN + k) * H_ + (n & 255)];
}

// ---------------- x-part GEMM: Xg[m][512] = A[m][K] @ WxT^T + bias (fp16 out) ---------
template<int KFULL, bool AF32>
__global__ __launch_bounds__(256) void gemm_xpart(const void* __restrict__ Av,
    const f16* __restrict__ Bt, const float* __restrict__ bf, const float* __restrict__ bc,
    f16* __restrict__ Xg) {
  __shared__ __align__(16) f16 As[128][72];   // +8 pad: kills 16-way bank conflicts
  __shared__ __align__(16) f16 Bs[128][72];
  const int m0 = blockIdx.x * 128, n0 = blockIdx.y * 128;
  const int tid = threadIdx.x, lane = tid & 63, wid = tid >> 6;
  const int wr = wid >> 1, wc = wid & 1;
  f32x4 zero4 = {0.f, 0.f, 0.f, 0.f};
  f32x4 acc[4][4];
  #pragma unroll
  for (int i = 0; i < 4; ++i)
    #pragma unroll
    for (int j = 0; j < 4; ++j) acc[i][j] = zero4;
  const int r2 = tid >> 1, hh = tid & 1;
  for (int kb = 0; kb < KFULL / 64; ++kb) {
    const int k0 = kb * 64;
    if (kb) __syncthreads();
    if (AF32) {
      const float* A = (const float*)Av;
      const float* src = A + (size_t)(m0 + r2) * KFULL + k0 + hh * 32;
      #pragma unroll
      for (int i = 0; i < 8; ++i) {
        float4 v = *(const float4*)(src + i * 4);
        f16x4 p = { (f16)v.x, (f16)v.y, (f16)v.z, (f16)v.w };
        *(f16x4*)&As[r2][hh * 32 + i * 4] = p;
      }
    } else {
      const f16* A = (const f16*)Av;
      const f16* src = A + (size_t)(m0 + r2) * KFULL + k0 + hh * 32;
      #pragma unroll
      for (int i = 0; i < 4; ++i)
        *(uint4*)&As[r2][hh * 32 + i * 8] = *(const uint4*)(src + i * 8);
    }
    {
      const f16* src = Bt + (size_t)(n0 + r2) * KFULL + k0 + hh * 32;
      #pragma unroll
      for (int i = 0; i < 4; ++i)
        *(uint4*)&Bs[r2][hh * 32 + i * 8] = *(const uint4*)(src + i * 8);
    }
    __syncthreads();
    #pragma unroll
    for (int kt = 0; kt < 2; ++kt) {
      f16x8 af[4], bfr[4];
      #pragma unroll
      for (int i = 0; i < 4; ++i)
        af[i] = *(const f16x8*)&As[wr * 64 + i * 16 + (lane & 15)][kt * 32 + (lane >> 4) * 8];
      #pragma unroll
      for (int j = 0; j < 4; ++j)
        bfr[j] = *(const f16x8*)&Bs[wc * 64 + j * 16 + (lane & 15)][kt * 32 + (lane >> 4) * 8];
      #pragma unroll
      for (int i = 0; i < 4; ++i)
        #pragma unroll
        for (int j = 0; j < 4; ++j)
          acc[i][j] = __builtin_amdgcn_mfma_f32_16x16x32_f16(af[i], bfr[j], acc[i][j], 0, 0, 0);
    }
  }
  const float* bias = (n0 < 256) ? bf : bc;
  #pragma unroll
  for (int j = 0; j < 4; ++j) {
    const int gn = n0 + wc * 64 + j * 16 + (lane & 15);
    const float bv = bias[gn & 255];
    #pragma unroll
    for (int i = 0; i < 4; ++i) {
      #pragma unroll
      for (int reg = 0; reg < 4; ++reg) {
        const int gm = m0 + wr * 64 + i * 16 + (lane >> 4) * 4 + reg;
        Xg[(size_t)gm * 512 + gn] = (f16)(acc[i][j][reg] + bv);
      }
    }
  }
}

// ---------------- MFMA recurrence: 16 batch rows per block, 4 blocks -----------------
// 8 waves; wave w owns columns [32w,32w+32) for both f (n) and c (n+256):
//   tiles nt = {32w, 32w+16, 256+32w, 256+32w+16}.
// Weights UT[n][k] in registers as MFMA A-fragments: uw[4][8] = 128 VGPR.
// h[16 m][256 k] f16 in LDS (pitch 264 -> conflict-free b128 frag reads), dbuf.
// mfma(U, h, acc): D row = n (reg dim), D col = m  => per lane: m = lane&15,
// n = nt + 4*(lane>>4) + reg  -> x/y/h addresses are contiguous f16x4 / float4.
// One barrier/step: s_waitcnt lgkmcnt(0) + s_barrier (keeps Xg prefetch in flight).
__global__ __launch_bounds__(512, 2) void rec(const f16* __restrict__ UT,
    const f16* __restrict__ Xg, float* __restrict__ yf, f16* __restrict__ yh,
    float* __restrict__ hid) {
  __shared__ __align__(16) f16 hbuf[2][16][264];
  const int tid = threadIdx.x;
  const int lane = tid & 63, w = tid >> 6;
  const int lr = lane & 15, lg = lane >> 4;
  const int m0 = blockIdx.x * 16;

  int nt[4] = { 32 * w, 32 * w + 16, 256 + 32 * w, 256 + 32 * w + 16 };

  // weight fragments (A operand): lane holds UT[nt + lr][kf*32 + lg*8 .. +7]
  f16x8 uw[4][8];
  #pragma unroll
  for (int tt = 0; tt < 4; ++tt)
    #pragma unroll
    for (int kf = 0; kf < 8; ++kf)
      uw[tt][kf] = *(const f16x8*)&UT[(size_t)(nt[tt] + lr) * 256 + kf * 32 + lg * 8];

  // zero initial h buffer (buf 0, incl. padding)
  {
    uint* hz = (uint*)&hbuf[0][0][0];
    for (int i = tid; i < 2112; i += 512) hz[i] = 0u;
  }

  // per-tile Xg pointers: row b = m0+lr, col nt + 4*lg (+reg)
  const f16* xp[4];
  #pragma unroll
  for (int tt = 0; tt < 4; ++tt)
    xp[tt] = Xg + ((size_t)(m0 + lr) * T_) * 512 + nt[tt] + 4 * lg;

  float hreg[2][4] = {{0.f,0.f,0.f,0.f},{0.f,0.f,0.f,0.f}};
  f16x4 xcur[4];
  #pragma unroll
  for (int tt = 0; tt < 4; ++tt) xcur[tt] = *(const f16x4*)xp[tt];

  const size_t ybase = (size_t)(m0 + lr) * T_ * H_;
  const int ycol0 = 32 * w + 4 * lg;

  __syncthreads();

  #pragma unroll 1
  for (int t = 0; t < T_; ++t) {
    // h fragments (B operand): lane holds h[m=lr][kf*32 + lg*8 .. +7]
    f16x8 hf[8];
    #pragma unroll
    for (int kf = 0; kf < 8; ++kf)
      hf[kf] = *(const f16x8*)&hbuf[t & 1][lr][kf * 32 + lg * 8];

    // prefetch next step's x-part (stays in flight across the lgkm-only barrier)
    const int tn = (t + 1 < T_) ? t + 1 : t;
    f16x4 xn[4];
    #pragma unroll
    for (int tt = 0; tt < 4; ++tt) xn[tt] = *(const f16x4*)(xp[tt] + (size_t)tn * 512);

    f32x4 acc[4];
    #pragma unroll
    for (int tt = 0; tt < 4; ++tt) acc[tt] = (f32x4){0.f, 0.f, 0.f, 0.f};
    #pragma unroll
    for (int kf = 0; kf < 8; ++kf)
      #pragma unroll
      for (int tt = 0; tt < 4; ++tt)
        acc[tt] = __builtin_amdgcn_mfma_f32_16x16x32_f16(uw[tt][kf], hf[kf], acc[tt], 0, 0, 0);

    // epilogue: f = sigmoid(pre_f), c = tanh(pre_c), h' = c + f*(h - c)
    f16x4 hn4[2];
    #pragma unroll
    for (int p = 0; p < 2; ++p) {
      #pragma unroll
      for (int r = 0; r < 4; ++r) {
        float pf = acc[p][r]     + (float)xcur[p][r];
        float pc = acc[2 + p][r] + (float)xcur[2 + p][r];
        float f  = __builtin_amdgcn_rcpf(1.f + __expf(-pf));
        float e2 = __expf(2.f * pc);
        float c  = 1.f - 2.f * __builtin_amdgcn_rcpf(e2 + 1.f);
        float hn = c + f * (hreg[p][r] - c);
        hreg[p][r] = hn;
        hn4[p][r] = (f16)hn;
      }
      *(f16x4*)&hbuf[(t + 1) & 1][lr][ycol0 + 16 * p] = hn4[p];
    }
    if (yh) {
      #pragma unroll
      for (int p = 0; p < 2; ++p)
        *(f16x4*)(yh + ybase + (size_t)t * H_ + ycol0 + 16 * p) = hn4[p];
    }
    if (yf) {
      #pragma unroll
      for (int p = 0; p < 2; ++p) {
        float4 yv = make_float4(hreg[p][0], hreg[p][1], hreg[p][2], hreg[p][3]);
        *(float4*)(yf + ybase + (size_t)t * H_ + ycol0 + 16 * p) = yv;
      }
    }
    if (t == T_ - 1) {
      #pragma unroll
      for (int p = 0; p < 2; ++p) {
        float4 hv = make_float4(hreg[p][0], hreg[p][1], hreg[p][2], hreg[p][3]);
        *(float4*)(hid + (size_t)(m0 + lr) * H_ + ycol0 + 16 * p) = hv;
      }
    }

    // single per-step barrier: drain LDS writes only (NOT vmcnt -> prefetch stays live)
    asm volatile("s_waitcnt lgkmcnt(0)" ::: "memory");
    __builtin_amdgcn_s_barrier();
    asm volatile("" ::: "memory");   // keep next-iter ds_reads from hoisting above barrier

    #pragma unroll
    for (int tt = 0; tt < 4; ++tt) xcur[tt] = xn[tt];
  }
}

extern "C" void kernel_launch(void* const* d_in, const int* in_sizes, int n_in,
                              void* d_out, int out_size, void* d_ws, size_t ws_size,
                              hipStream_t stream) {
  (void)in_sizes; (void)n_in; (void)out_size; (void)ws_size;
  const float* x   = (const float*)d_in[0];
  const float* Wf1 = (const float*)d_in[1];
  const float* bf1 = (const float*)d_in[2];
  const float* Wc1 = (const float*)d_in[3];
  const float* bc1 = (const float*)d_in[4];
  const float* Wf2 = (const float*)d_in[5];
  const float* bf2 = (const float*)d_in[6];
  const float* Wc2 = (const float*)d_in[7];
  const float* bc2 = (const float*)d_in[8];
  float* out = (float*)d_out;

  char* ws = (char*)d_ws;
  f16*  Xg   = (f16*)(ws);                          // 64*1024*512*2  = 67108864 B
  f16*  y1h  = (f16*)(ws + 67108864);               // 64*1024*256*2  = 33554432 B
  f16*  Wx1T = (f16*)(ws + 100663296);              // 512*128*2      = 131072 B
  f16*  Wx2T = (f16*)(ws + 100794368);              // 512*256*2      = 262144 B
  f16*  UT1  = (f16*)(ws + 101056512);              // 512*256*2      = 262144 B
  f16*  UT2  = (f16*)(ws + 101318656);              // 512*256*2      = 262144 B

  float* y2   = out;                                // [64,1024,256]
  float* hid1 = out + (size_t)B_ * T_ * H_;         // [64,256]
  float* hid2 = hid1 + (size_t)B_ * H_;             // [64,256]

  prep_wxt<128><<<256, 256, 0, stream>>>(Wf1, Wc1, Wx1T);
  prep_wxt<256><<<512, 256, 0, stream>>>(Wf2, Wc2, Wx2T);
  prep_ut<<<512, 256, 0, stream>>>(Wf1, Wc1, UT1, 128);
  prep_ut<<<512, 256, 0, stream>>>(Wf2, Wc2, UT2, 256);

  gemm_xpart<128, true ><<<dim3(512, 4), 256, 0, stream>>>(x,   Wx1T, bf1, bc1, Xg);
  rec<<<4, 512, 0, stream>>>(UT1, Xg, nullptr, y1h, hid1);
  gemm_xpart<256, false><<<dim3(512, 4), 256, 0, stream>>>(y1h, Wx2T, bf2, bc2, Xg);
  rec<<<4, 512, 0, stream>>>(UT2, Xg, y2, nullptr, hid2);
}

// Round 2
// 2624.603 us; speedup vs baseline: 1.0002x; 1.0002x over previous
//
#include <hip/hip_runtime.h>

typedef unsigned int uint;
typedef _Float16 f16;
typedef _Float16 f16x2 __attribute__((ext_vector_type(2)));
typedef _Float16 f16x4 __attribute__((ext_vector_type(4)));
typedef _Float16 f16x8 __attribute__((ext_vector_type(8)));
typedef float f32x4 __attribute__((ext_vector_type(4)));

#define B_ 64
#define T_ 1024
#define I_ 128
#define H_ 256

// ---------------- prep: transpose x-part weights to [512 cols][K] fp16 ----------------
template<int KIN>
__global__ void prep_wxt(const float* __restrict__ Wf, const float* __restrict__ Wc,
                         f16* __restrict__ WxT) {
  int o = blockIdx.x * 256 + threadIdx.x;
  if (o >= 512 * KIN) return;
  int n = o / KIN, k = o % KIN;
  float v = (n < 256) ? Wf[k * H_ + n] : Wc[k * H_ + (n - 256)];
  WxT[o] = (f16)v;
}

// ---------------- prep: transpose recurrent weights to UT[512 n][256 k] fp16 ----------
// UT[n][k] = W[(DIN+k)*H + (n&255)], gate = n>>8 (0=f from Wf, 1=c from Wc)
__global__ void prep_ut(const float* __restrict__ Wf, const float* __restrict__ Wc,
                        f16* __restrict__ UT, int DIN) {
  int o = blockIdx.x * 256 + threadIdx.x;   // 512*256 = 131072
  int n = o >> 8, k = o & 255;
  const float* W = (n < 256) ? Wf : Wc;
  UT[o] = (f16)W[(DIN + k) * H_ + (n & 255)];
}

// ---------------- x-part GEMM: Xg[m][512] = A[m][K] @ WxT^T + bias (fp16 out) ---------
template<int KFULL, bool AF32>
__global__ __launch_bounds__(256) void gemm_xpart(const void* __restrict__ Av,
    const f16* __restrict__ Bt, const float* __restrict__ bf, const float* __restrict__ bc,
    f16* __restrict__ Xg) {
  __shared__ __align__(16) f16 As[128][72];   // +8 pad: kills 16-way bank conflicts
  __shared__ __align__(16) f16 Bs[128][72];
  const int m0 = blockIdx.x * 128, n0 = blockIdx.y * 128;
  const int tid = threadIdx.x, lane = tid & 63, wid = tid >> 6;
  const int wr = wid >> 1, wc = wid & 1;
  f32x4 zero4 = {0.f, 0.f, 0.f, 0.f};
  f32x4 acc[4][4];
  #pragma unroll
  for (int i = 0; i < 4; ++i)
    #pragma unroll
    for (int j = 0; j < 4; ++j) acc[i][j] = zero4;
  const int r2 = tid >> 1, hh = tid & 1;
  for (int kb = 0; kb < KFULL / 64; ++kb) {
    const int k0 = kb * 64;
    if (kb) __syncthreads();
    if (AF32) {
      const float* A = (const float*)Av;
      const float* src = A + (size_t)(m0 + r2) * KFULL + k0 + hh * 32;
      #pragma unroll
      for (int i = 0; i < 8; ++i) {
        float4 v = *(const float4*)(src + i * 4);
        f16x4 p = { (f16)v.x, (f16)v.y, (f16)v.z, (f16)v.w };
        *(f16x4*)&As[r2][hh * 32 + i * 4] = p;
      }
    } else {
      const f16* A = (const f16*)Av;
      const f16* src = A + (size_t)(m0 + r2) * KFULL + k0 + hh * 32;
      #pragma unroll
      for (int i = 0; i < 4; ++i)
        *(uint4*)&As[r2][hh * 32 + i * 8] = *(const uint4*)(src + i * 8);
    }
    {
      const f16* src = Bt + (size_t)(n0 + r2) * KFULL + k0 + hh * 32;
      #pragma unroll
      for (int i = 0; i < 4; ++i)
        *(uint4*)&Bs[r2][hh * 32 + i * 8] = *(const uint4*)(src + i * 8);
    }
    __syncthreads();
    #pragma unroll
    for (int kt = 0; kt < 2; ++kt) {
      f16x8 af[4], bfr[4];
      #pragma unroll
      for (int i = 0; i < 4; ++i)
        af[i] = *(const f16x8*)&As[wr * 64 + i * 16 + (lane & 15)][kt * 32 + (lane >> 4) * 8];
      #pragma unroll
      for (int j = 0; j < 4; ++j)
        bfr[j] = *(const f16x8*)&Bs[wc * 64 + j * 16 + (lane & 15)][kt * 32 + (lane >> 4) * 8];
      #pragma unroll
      for (int i = 0; i < 4; ++i)
        #pragma unroll
        for (int j = 0; j < 4; ++j)
          acc[i][j] = __builtin_amdgcn_mfma_f32_16x16x32_f16(af[i], bfr[j], acc[i][j], 0, 0, 0);
    }
  }
  const float* bias = (n0 < 256) ? bf : bc;
  #pragma unroll
  for (int j = 0; j < 4; ++j) {
    const int gn = n0 + wc * 64 + j * 16 + (lane & 15);
    const float bv = bias[gn & 255];
    #pragma unroll
    for (int i = 0; i < 4; ++i) {
      #pragma unroll
      for (int reg = 0; reg < 4; ++reg) {
        const int gm = m0 + wr * 64 + i * 16 + (lane >> 4) * 4 + reg;
        Xg[(size_t)gm * 512 + gn] = (f16)(acc[i][j][reg] + bv);
      }
    }
  }
}

// ---------------- MFMA recurrence: 16 batch rows per block, 4 blocks, 16 waves -------
// Wave w (0..15) owns f-tile n=16w and c-tile n=256+16w.  Per-wave weights:
// uwf[8]+uwc[8] = 64 VGPR (fits the 128-reg budget 4 waves/SIMD requires ->
// register-resident; R1's 8-wave version demoted its 128-reg array, VGPR=100).
// h[16 m][256 k] f16 in LDS (pitch 264), double-buffered; per step per wave:
// 8 ds_read_b128 (2 chunks of 4 to cap live regs) + 16 mfma_16x16x32_f16 +
// 4-output epilogue.  mfma(U, h, acc): lane holds m=lane&15, n=16w+4*(lane>>4)+reg
// -> x/h/y addresses contiguous f16x4.  One lgkm-only barrier per step.
__global__ __launch_bounds__(1024, 4) void rec(const f16* __restrict__ UT,
    const f16* __restrict__ Xg, float* __restrict__ yf, f16* __restrict__ yh,
    float* __restrict__ hid) {
  __shared__ __align__(16) f16 hbuf[2][16][264];
  const int tid = threadIdx.x;
  const int lane = tid & 63, w = tid >> 6;          // w = 0..15
  const int lr = lane & 15, lg = lane >> 4;
  const int m0 = blockIdx.x * 16;

  const int nf = 16 * w;            // f-gate tile base column (0..240)
  const int nc = 256 + 16 * w;      // candidate tile base column

  // weight fragments (A operand): lane holds UT[n + lr][kf*32 + lg*8 .. +7]
  f16x8 uwf[8], uwc[8];
  #pragma unroll
  for (int kf = 0; kf < 8; ++kf) {
    uwf[kf] = *(const f16x8*)&UT[(size_t)(nf + lr) * 256 + kf * 32 + lg * 8];
    uwc[kf] = *(const f16x8*)&UT[(size_t)(nc + lr) * 256 + kf * 32 + lg * 8];
  }

  // zero initial h buffer (buf 0, incl. padding)
  {
    uint* hz = (uint*)&hbuf[0][0][0];
    for (int i = tid; i < 2112; i += 1024) hz[i] = 0u;
  }

  // x-part pointers: row b = m0+lr, f col = nf + 4lg, c col = +256
  const f16* xpf = Xg + ((size_t)(m0 + lr) * T_) * 512 + nf + 4 * lg;
  const f16* xpc = xpf + 256;

  float hreg[4] = {0.f, 0.f, 0.f, 0.f};
  f16x4 xf = *(const f16x4*)xpf;
  f16x4 xc = *(const f16x4*)xpc;

  const size_t ybase = (size_t)(m0 + lr) * T_ * H_;
  const int ycol0 = nf + 4 * lg;    // 0..255, 4 consecutive h columns per lane

  __syncthreads();

  #pragma unroll 1
  for (int t = 0; t < T_; ++t) {
    // prefetch next step's x-part first (deep in the vmcnt queue; consumed at
    // the very end of this iteration -> latency hidden under MFMA + epilogue)
    const int tn = (t + 1 < T_) ? t + 1 : t;
    f16x4 xfn = *(const f16x4*)(xpf + (size_t)tn * 512);
    f16x4 xcn = *(const f16x4*)(xpc + (size_t)tn * 512);

    const f16* hrow = &hbuf[t & 1][lr][0];
    f32x4 accf = {0.f, 0.f, 0.f, 0.f};
    f32x4 accc = {0.f, 0.f, 0.f, 0.f};
    // two chunks of 4 k-fragments: caps live hf regs at 16, stays in 128-budget
    #pragma unroll
    for (int c = 0; c < 2; ++c) {
      f16x8 h0 = *(const f16x8*)(hrow + (4 * c + 0) * 32 + lg * 8);
      f16x8 h1 = *(const f16x8*)(hrow + (4 * c + 1) * 32 + lg * 8);
      f16x8 h2 = *(const f16x8*)(hrow + (4 * c + 2) * 32 + lg * 8);
      f16x8 h3 = *(const f16x8*)(hrow + (4 * c + 3) * 32 + lg * 8);
      // f/c alternated: dependent MFMAs 2 apart -> no single-chain latency stall
      accf = __builtin_amdgcn_mfma_f32_16x16x32_f16(uwf[4 * c + 0], h0, accf, 0, 0, 0);
      accc = __builtin_amdgcn_mfma_f32_16x16x32_f16(uwc[4 * c + 0], h0, accc, 0, 0, 0);
      accf = __builtin_amdgcn_mfma_f32_16x16x32_f16(uwf[4 * c + 1], h1, accf, 0, 0, 0);
      accc = __builtin_amdgcn_mfma_f32_16x16x32_f16(uwc[4 * c + 1], h1, accc, 0, 0, 0);
      accf = __builtin_amdgcn_mfma_f32_16x16x32_f16(uwf[4 * c + 2], h2, accf, 0, 0, 0);
      accc = __builtin_amdgcn_mfma_f32_16x16x32_f16(uwc[4 * c + 2], h2, accc, 0, 0, 0);
      accf = __builtin_amdgcn_mfma_f32_16x16x32_f16(uwf[4 * c + 3], h3, accf, 0, 0, 0);
      accc = __builtin_amdgcn_mfma_f32_16x16x32_f16(uwc[4 * c + 3], h3, accc, 0, 0, 0);
    }

    // epilogue: f = sigmoid(pre_f), c = tanh(pre_c), h' = c + f*(h - c)
    f16x4 hn4;
    #pragma unroll
    for (int r = 0; r < 4; ++r) {
      float pf = accf[r] + (float)xf[r];
      float pc = accc[r] + (float)xc[r];
      float fg = __builtin_amdgcn_rcpf(1.f + __expf(-pf));
      float e2 = __expf(2.f * pc);
      float cc = 1.f - 2.f * __builtin_amdgcn_rcpf(e2 + 1.f);
      float hn = cc + fg * (hreg[r] - cc);
      hreg[r] = hn;
      hn4[r] = (f16)hn;
    }
    *(f16x4*)&hbuf[(t + 1) & 1][lr][ycol0] = hn4;
    if (yh) *(f16x4*)(yh + ybase + (size_t)t * H_ + ycol0) = hn4;
    if (yf) {
      float4 yv = make_float4(hreg[0], hreg[1], hreg[2], hreg[3]);
      *(float4*)(yf + ybase + (size_t)t * H_ + ycol0) = yv;
    }
    if (t == T_ - 1) {
      float4 hv = make_float4(hreg[0], hreg[1], hreg[2], hreg[3]);
      *(float4*)(hid + (size_t)(m0 + lr) * H_ + ycol0) = hv;
    }

    // single per-step barrier: drain LDS writes only (NOT vmcnt -> x prefetch live)
    asm volatile("s_waitcnt lgkmcnt(0)" ::: "memory");
    __builtin_amdgcn_s_barrier();
    asm volatile("" ::: "memory");   // keep next-iter ds_reads from hoisting above barrier

    xf = xfn;
    xc = xcn;
  }
}

extern "C" void kernel_launch(void* const* d_in, const int* in_sizes, int n_in,
                              void* d_out, int out_size, void* d_ws, size_t ws_size,
                              hipStream_t stream) {
  (void)in_sizes; (void)n_in; (void)out_size; (void)ws_size;
  const float* x   = (const float*)d_in[0];
  const float* Wf1 = (const float*)d_in[1];
  const float* bf1 = (const float*)d_in[2];
  const float* Wc1 = (const float*)d_in[3];
  const float* bc1 = (const float*)d_in[4];
  const float* Wf2 = (const float*)d_in[5];
  const float* bf2 = (const float*)d_in[6];
  const float* Wc2 = (const float*)d_in[7];
  const float* bc2 = (const float*)d_in[8];
  float* out = (float*)d_out;

  char* ws = (char*)d_ws;
  f16*  Xg   = (f16*)(ws);                          // 64*1024*512*2  = 67108864 B
  f16*  y1h  = (f16*)(ws + 67108864);               // 64*1024*256*2  = 33554432 B
  f16*  Wx1T = (f16*)(ws + 100663296);              // 512*128*2      = 131072 B
  f16*  Wx2T = (f16*)(ws + 100794368);              // 512*256*2      = 262144 B
  f16*  UT1  = (f16*)(ws + 101056512);              // 512*256*2      = 262144 B
  f16*  UT2  = (f16*)(ws + 101318656);              // 512*256*2      = 262144 B

  float* y2   = out;                                // [64,1024,256]
  float* hid1 = out + (size_t)B_ * T_ * H_;         // [64,256]
  float* hid2 = hid1 + (size_t)B_ * H_;             // [64,256]

  prep_wxt<128><<<256, 256, 0, stream>>>(Wf1, Wc1, Wx1T);
  prep_wxt<256><<<512, 256, 0, stream>>>(Wf2, Wc2, Wx2T);
  prep_ut<<<512, 256, 0, stream>>>(Wf1, Wc1, UT1, 128);
  prep_ut<<<512, 256, 0, stream>>>(Wf2, Wc2, UT2, 256);

  gemm_xpart<128, true ><<<dim3(512, 4), 256, 0, stream>>>(x,   Wx1T, bf1, bc1, Xg);
  rec<<<4, 1024, 0, stream>>>(UT1, Xg, nullptr, y1h, hid1);
  gemm_xpart<256, false><<<dim3(512, 4), 256, 0, stream>>>(y1h, Wx2T, bf2, bc2, Xg);
  rec<<<4, 1024, 0, stream>>>(UT2, Xg, y2, nullptr, hid2);
}